// Round 9
// baseline (1872.009 us; speedup 1.0000x reference)
//
#include <hip/hip_runtime.h>
#include <math.h>

typedef _Float16 h16;
typedef _Float16 h16x2 __attribute__((ext_vector_type(2)));

#define NS 65536      // samples per class (big / small)
#define VSTR 131072   // xvec/fmag column count (4096 batches * 32 vectors)

// ---------------- k_gather: x -> xvec columns (fp32); block 4096 builds twiddles ----
__global__ __launch_bounds__(256) void k_gather(const float* __restrict__ x,
                                                float* __restrict__ xv,
                                                float* __restrict__ tw) {
  const int b = blockIdx.x;
  if (b < 4096) {
    const float* xb = x + (size_t)b * 9152;
    const int base = b * 32;
    for (int i = threadIdx.x; i < 9152; i += 256) {
      float v = xb[i];
      int c = i >> 6, pos = i & 63;
      if (pos >= 24 && pos < 40)
        xv[(size_t)c * VSTR + base + (pos - 24)] = v;
      int wc = pos & 7;
      if (wc == 3 || wc == 4)
        xv[(size_t)c * VSTR + base + 16 + ((pos >> 3) << 1) + (wc - 3)] = v;
    }
  } else {
    for (int i = threadIdx.x; i < 10296; i += 256) {
      int k = i / 143, n = i - k * 143;
      int e = (k * n) % 143;
      float ang = 6.2831853071795864769f * (float)e / 143.0f;
      float s, c;
      sincosf(ang, &s, &c);
      tw[2 * i] = c;
      tw[2 * i + 1] = s;
    }
  }
}

// ---------------- k_dft: lane = vector, column in VGPRs, uniform twiddles ----
__global__ __launch_bounds__(256, 2) void k_dft(const float* __restrict__ xv,
                                                const float* __restrict__ tw,
                                                h16* __restrict__ fm) {
  const int v = blockIdx.x * 256 + threadIdx.x;
  float xr[143];
#pragma unroll
  for (int n = 0; n < 143; ++n) xr[n] = xv[(size_t)n * VSTR + v];

  for (int k = 0; k < 72; ++k) {
    const float* __restrict__ twk = tw + k * 286;
    float re = 0.f, im = 0.f;
#pragma unroll
    for (int n = 0; n < 143; ++n) {
      re = fmaf(xr[n], twk[2 * n], re);
      im = fmaf(xr[n], twk[2 * n + 1], im);
    }
    float m = sqrtf(re * re + im * im);
    fm[(size_t)k * VSTR + v] = (h16)m;
    if (k) fm[(size_t)(143 - k) * VSTR + v] = (h16)m;
  }
}

// R6 uniform-block mapping (verified 1161us): every block does big + small work,
// immune to dispatch-order imbalance (R4/R5 lesson). R9 bisect: keep k_c1/k_c2
// from R6 verbatim; apply ONLY the c3+c4 fusion (R7/R8 double-failure ambiguity:
// this isolates the c34 fusion; c12 fusion deferred).
__device__ __forceinline__ void smap(int& d, int& w, int& va, int& vb,
                                     int& bi, int& u) {
  int lane = threadIdx.x & 63;
  w = __builtin_amdgcn_readfirstlane(threadIdx.x >> 6);
  d = (int)blockIdx.x * 64 + lane;
  bi = d >> 4;
  u = d & 15;
  va = (u < 8) ? bi * 32 + ((u >> 2) << 3) + ((u & 3) << 1)
               : bi * 32 + 16 + ((u & 7) << 1);
  vb = va + 1;
}

// ---------------- k_c1: conv1 -> LN1 stats (no z1 store); big then small ------
__global__ __launch_bounds__(256, 2) void k_c1(const float* __restrict__ xv,
                                               const h16* __restrict__ fm,
                                               const float* __restrict__ w1,
                                               const float* __restrict__ f1,
                                               float* __restrict__ s1) {
  int d, w, va, vb, bi, u;
  smap(d, w, va, vb, bi, u);

  // ---- big: channels 4w..4w+3 ----
  {
    float sum[4] = {0, 0, 0, 0}, sq[4] = {0, 0, 0, 0};
    float A0 = xv[va], B0 = xv[vb];
    for (int p = 0; p < 71; ++p) {
      float A1 = xv[(size_t)(2 * p + 1) * VSTR + va];
      float A2 = xv[(size_t)(2 * p + 2) * VSTR + va];
      float B1 = xv[(size_t)(2 * p + 1) * VSTR + vb];
      float B2 = xv[(size_t)(2 * p + 2) * VSTR + vb];
#pragma unroll
      for (int j = 0; j < 4; ++j) {
        const float* wp = w1 + (4 * w + j) * 6;
        float v = A0 * wp[0];
        v = fmaf(A1, wp[1], v); v = fmaf(A2, wp[2], v);
        v = fmaf(B0, wp[3], v); v = fmaf(B1, wp[4], v); v = fmaf(B2, wp[5], v);
        sum[j] += v; sq[j] = fmaf(v, v, sq[j]);
      }
      A0 = A2; B0 = B2;
    }
#pragma unroll
    for (int j = 0; j < 4; ++j) {
      float mu = sum[j] * (1.0f / 71.0f);
      float var = sq[j] * (1.0f / 71.0f) - mu * mu;
      s1[(size_t)(4 * w + j) * NS + d] = mu;
      s1[(size_t)(16 + 4 * w + j) * NS + d] = rsqrtf(var + 1e-5f);
    }
  }
  // ---- small: channel w ----
  {
    float sum = 0.f, sq = 0.f;
    const float* wp = f1 + w * 6;
    float A0 = (float)fm[va], B0 = (float)fm[vb];
    for (int p = 0; p < 71; ++p) {
      float A1 = (float)fm[(size_t)(2 * p + 1) * VSTR + va];
      float A2 = (float)fm[(size_t)(2 * p + 2) * VSTR + va];
      float B1 = (float)fm[(size_t)(2 * p + 1) * VSTR + vb];
      float B2 = (float)fm[(size_t)(2 * p + 2) * VSTR + vb];
      float v = A0 * wp[0];
      v = fmaf(A1, wp[1], v); v = fmaf(A2, wp[2], v);
      v = fmaf(B0, wp[3], v); v = fmaf(B1, wp[4], v); v = fmaf(B2, wp[5], v);
      sum += v; sq = fmaf(v, v, sq);
      A0 = A2; B0 = B2;
    }
    float mu = sum * (1.0f / 71.0f);
    float var = sq * (1.0f / 71.0f) - mu * mu;
    s1[(size_t)(32 + w) * NS + d] = mu;
    s1[(size_t)(36 + w) * NS + d] = rsqrtf(var + 1e-5f);
  }
}

// -------- k_c2: conv1(recomp ONCE) + LN1-apply + conv2 + LN2 stats -> z2 (fp16) ----
// R6 verbatim (verified 342us): 4-wave p-split, rolling window, 32KB LDS reduce.
__global__ __launch_bounds__(256, 2) void k_c2(const float* __restrict__ xv,
                                               const h16* __restrict__ fm,
                                               const float* __restrict__ w1,
                                               const float* __restrict__ w2,
                                               const float* __restrict__ f1,
                                               const float* __restrict__ f2,
                                               const float* __restrict__ l1g,
                                               const float* __restrict__ l1b,
                                               const float* __restrict__ s1,
                                               h16* __restrict__ z2,
                                               float* __restrict__ s2) {
  __shared__ float red[4][32][64];
  const int lane = threadIdx.x & 63;
  const int w = threadIdx.x >> 6;           // wave id = p-chunk id
  const int d = (int)blockIdx.x * 64 + lane;
  const int bi = d >> 4, u = d & 15;
  const int va = (u < 8) ? bi * 32 + ((u >> 2) << 3) + ((u & 3) << 1)
                         : bi * 32 + 16 + ((u & 7) << 1);
  const int ps = w * 9;
  const int pe = (ps + 9 < 35) ? (ps + 9) : 35;

  float sum[28], sq[28];     // big stats
  float sums[4], sqs[4];     // small stats

  // ================= big phase =================
  {
    float mu1[16], inv1[16];
#pragma unroll
    for (int c = 0; c < 16; ++c) {
      mu1[c] = s1[(size_t)c * NS + d];
      inv1[c] = s1[(size_t)(16 + c) * NS + d];
    }
#pragma unroll
    for (int j = 0; j < 28; ++j) { sum[j] = 0.f; sq[j] = 0.f; }

    float n0[16], n1[16], n2[16];
    float a2, b2, a3, b3, a4, b4, a5, b5, a6, b6;

    {
      float2 r0 = *(const float2*)(xv + (size_t)(4 * ps) * VSTR + va);
      float2 r1 = *(const float2*)(xv + (size_t)(4 * ps + 1) * VSTR + va);
      float2 r2 = *(const float2*)(xv + (size_t)(4 * ps + 2) * VSTR + va);
      a2 = r2.x; b2 = r2.y;
      const float gg = l1g[2 * ps], bb = l1b[2 * ps];
#pragma unroll
      for (int c = 0; c < 16; ++c) {
        const float* wp = w1 + c * 6;
        float v = r0.x * wp[0];
        v = fmaf(r1.x, wp[1], v); v = fmaf(a2, wp[2], v);
        v = fmaf(r0.y, wp[3], v); v = fmaf(r1.y, wp[4], v); v = fmaf(b2, wp[5], v);
        n0[c] = fmaxf(fmaf((v - mu1[c]) * inv1[c], gg, bb), 0.f);
      }
      float2 r3 = *(const float2*)(xv + (size_t)(4 * ps + 3) * VSTR + va);
      float2 r4 = *(const float2*)(xv + (size_t)(4 * ps + 4) * VSTR + va);
      float2 r5 = *(const float2*)(xv + (size_t)(4 * ps + 5) * VSTR + va);
      float2 r6 = *(const float2*)(xv + (size_t)(4 * ps + 6) * VSTR + va);
      a3 = r3.x; b3 = r3.y; a4 = r4.x; b4 = r4.y;
      a5 = r5.x; b5 = r5.y; a6 = r6.x; b6 = r6.y;
    }

#pragma unroll 1
    for (int p = ps; p < pe; ++p) {
      {
        const float gg = l1g[2 * p + 1], bb = l1b[2 * p + 1];
#pragma unroll
        for (int c = 0; c < 16; ++c) {
          const float* wp = w1 + c * 6;
          float v = a2 * wp[0];
          v = fmaf(a3, wp[1], v); v = fmaf(a4, wp[2], v);
          v = fmaf(b2, wp[3], v); v = fmaf(b3, wp[4], v); v = fmaf(b4, wp[5], v);
          n1[c] = fmaxf(fmaf((v - mu1[c]) * inv1[c], gg, bb), 0.f);
        }
      }
      {
        const float gg = l1g[2 * p + 2], bb = l1b[2 * p + 2];
#pragma unroll
        for (int c = 0; c < 16; ++c) {
          const float* wp = w1 + c * 6;
          float v = a4 * wp[0];
          v = fmaf(a5, wp[1], v); v = fmaf(a6, wp[2], v);
          v = fmaf(b4, wp[3], v); v = fmaf(b5, wp[4], v); v = fmaf(b6, wp[5], v);
          n2[c] = fmaxf(fmaf((v - mu1[c]) * inv1[c], gg, bb), 0.f);
        }
      }
      a2 = a6; b2 = b6;
      {
        const int rbase = (p < 34) ? (4 * p + 7) : 139;
        const float* rp = xv + (size_t)rbase * VSTR + va;
        float2 r3 = *(const float2*)(rp);
        float2 r4 = *(const float2*)(rp + (size_t)VSTR);
        float2 r5 = *(const float2*)(rp + (size_t)2 * VSTR);
        float2 r6 = *(const float2*)(rp + (size_t)3 * VSTR);
        a3 = r3.x; b3 = r3.y; a4 = r4.x; b4 = r4.y;
        a5 = r5.x; b5 = r5.y; a6 = r6.x; b6 = r6.y;
      }
#pragma unroll
      for (int j = 0; j < 28; ++j) {
        const float* wp = w2 + j * 48;
        float acc = 0.f;
#pragma unroll
        for (int ci = 0; ci < 16; ++ci) {
          acc = fmaf(n0[ci], wp[ci * 3 + 0], acc);
          acc = fmaf(n1[ci], wp[ci * 3 + 1], acc);
          acc = fmaf(n2[ci], wp[ci * 3 + 2], acc);
        }
        z2[(size_t)(j * 35 + p) * NS + d] = (h16)acc;
        sum[j] += acc; sq[j] = fmaf(acc, acc, sq[j]);
      }
#pragma unroll
      for (int c = 0; c < 16; ++c) n0[c] = n2[c];
    }
  }

  // ================= small phase =================
  {
    float mu1[4], inv1[4];
#pragma unroll
    for (int c = 0; c < 4; ++c) {
      mu1[c] = s1[(size_t)(32 + c) * NS + d];
      inv1[c] = s1[(size_t)(36 + c) * NS + d];
    }
#pragma unroll
    for (int c = 0; c < 4; ++c) { sums[c] = 0.f; sqs[c] = 0.f; }
    float n0[4], n1[4], n2[4];
    float a2, b2, a3, b3, a4, b4, a5, b5, a6, b6;

    {
      h16x2 r0 = *(const h16x2*)(fm + (size_t)(4 * ps) * VSTR + va);
      h16x2 r1 = *(const h16x2*)(fm + (size_t)(4 * ps + 1) * VSTR + va);
      h16x2 r2 = *(const h16x2*)(fm + (size_t)(4 * ps + 2) * VSTR + va);
      float a0 = (float)r0.x, b0 = (float)r0.y;
      float a1 = (float)r1.x, b1 = (float)r1.y;
      a2 = (float)r2.x; b2 = (float)r2.y;
      const float gg = l1g[2 * ps], bb = l1b[2 * ps];
#pragma unroll
      for (int c = 0; c < 4; ++c) {
        const float* wp = f1 + c * 6;
        float v = a0 * wp[0];
        v = fmaf(a1, wp[1], v); v = fmaf(a2, wp[2], v);
        v = fmaf(b0, wp[3], v); v = fmaf(b1, wp[4], v); v = fmaf(b2, wp[5], v);
        n0[c] = fmaxf(fmaf((v - mu1[c]) * inv1[c], gg, bb), 0.f);
      }
      h16x2 r3 = *(const h16x2*)(fm + (size_t)(4 * ps + 3) * VSTR + va);
      h16x2 r4 = *(const h16x2*)(fm + (size_t)(4 * ps + 4) * VSTR + va);
      h16x2 r5 = *(const h16x2*)(fm + (size_t)(4 * ps + 5) * VSTR + va);
      h16x2 r6 = *(const h16x2*)(fm + (size_t)(4 * ps + 6) * VSTR + va);
      a3 = (float)r3.x; b3 = (float)r3.y; a4 = (float)r4.x; b4 = (float)r4.y;
      a5 = (float)r5.x; b5 = (float)r5.y; a6 = (float)r6.x; b6 = (float)r6.y;
    }

#pragma unroll 1
    for (int p = ps; p < pe; ++p) {
      {
        const float gg = l1g[2 * p + 1], bb = l1b[2 * p + 1];
#pragma unroll
        for (int c = 0; c < 4; ++c) {
          const float* wp = f1 + c * 6;
          float v = a2 * wp[0];
          v = fmaf(a3, wp[1], v); v = fmaf(a4, wp[2], v);
          v = fmaf(b2, wp[3], v); v = fmaf(b3, wp[4], v); v = fmaf(b4, wp[5], v);
          n1[c] = fmaxf(fmaf((v - mu1[c]) * inv1[c], gg, bb), 0.f);
        }
      }
      {
        const float gg = l1g[2 * p + 2], bb = l1b[2 * p + 2];
#pragma unroll
        for (int c = 0; c < 4; ++c) {
          const float* wp = f1 + c * 6;
          float v = a4 * wp[0];
          v = fmaf(a5, wp[1], v); v = fmaf(a6, wp[2], v);
          v = fmaf(b4, wp[3], v); v = fmaf(b5, wp[4], v); v = fmaf(b6, wp[5], v);
          n2[c] = fmaxf(fmaf((v - mu1[c]) * inv1[c], gg, bb), 0.f);
        }
      }
      a2 = a6; b2 = b6;
      {
        const int rbase = (p < 34) ? (4 * p + 7) : 139;
        const h16* rp = fm + (size_t)rbase * VSTR + va;
        h16x2 r3 = *(const h16x2*)(rp);
        h16x2 r4 = *(const h16x2*)(rp + (size_t)VSTR);
        h16x2 r5 = *(const h16x2*)(rp + (size_t)2 * VSTR);
        h16x2 r6 = *(const h16x2*)(rp + (size_t)3 * VSTR);
        a3 = (float)r3.x; b3 = (float)r3.y; a4 = (float)r4.x; b4 = (float)r4.y;
        a5 = (float)r5.x; b5 = (float)r5.y; a6 = (float)r6.x; b6 = (float)r6.y;
      }
#pragma unroll
      for (int co = 0; co < 4; ++co) {
        const float* wpo = f2 + co * 12;
        float acc = 0.f;
#pragma unroll
        for (int c = 0; c < 4; ++c) acc = fmaf(n0[c], wpo[c * 3 + 0], acc);
#pragma unroll
        for (int c = 0; c < 4; ++c) acc = fmaf(n1[c], wpo[c * 3 + 1], acc);
#pragma unroll
        for (int c = 0; c < 4; ++c) acc = fmaf(n2[c], wpo[c * 3 + 2], acc);
        z2[(size_t)(980 + co * 35 + p) * NS + d] = (h16)acc;
        sums[co] += acc; sqs[co] = fmaf(acc, acc, sqs[co]);
      }
#pragma unroll
      for (int c = 0; c < 4; ++c) n0[c] = n2[c];
    }
  }

  // ============ cross-wave LN2-stat reduction (32KB LDS, 2 phases) ============
#pragma unroll
  for (int j = 0; j < 28; ++j) red[w][j][lane] = sum[j];
#pragma unroll
  for (int c = 0; c < 4; ++c) red[w][28 + c][lane] = sums[c];
  __syncthreads();
  const int jb = 7 * w;
  float fs[7], fq[7];
#pragma unroll
  for (int t = 0; t < 7; ++t)
    fs[t] = red[0][jb + t][lane] + red[1][jb + t][lane] +
            red[2][jb + t][lane] + red[3][jb + t][lane];
  float fss = red[0][28 + w][lane] + red[1][28 + w][lane] +
              red[2][28 + w][lane] + red[3][28 + w][lane];
  __syncthreads();
#pragma unroll
  for (int j = 0; j < 28; ++j) red[w][j][lane] = sq[j];
#pragma unroll
  for (int c = 0; c < 4; ++c) red[w][28 + c][lane] = sqs[c];
  __syncthreads();
#pragma unroll
  for (int t = 0; t < 7; ++t)
    fq[t] = red[0][jb + t][lane] + red[1][jb + t][lane] +
            red[2][jb + t][lane] + red[3][jb + t][lane];
  float fqs = red[0][28 + w][lane] + red[1][28 + w][lane] +
              red[2][28 + w][lane] + red[3][28 + w][lane];
#pragma unroll
  for (int t = 0; t < 7; ++t) {
    float mu = fs[t] * (1.0f / 35.0f);
    float var = fq[t] * (1.0f / 35.0f) - mu * mu;
    s2[(size_t)(jb + t) * NS + d] = mu;
    s2[(size_t)(28 + jb + t) * NS + d] = rsqrtf(var + 1e-5f);
  }
  {
    float mu = fss * (1.0f / 35.0f);
    float var = fqs * (1.0f / 35.0f) - mu * mu;
    s2[(size_t)(56 + w) * NS + d] = mu;
    s2[(size_t)(60 + w) * NS + d] = rsqrtf(var + 1e-5f);
  }
}

// -------- k_c34: LN2+conv3+LN3(f32)->LDS->conv4+LN4 -> out; LDS time-shared ----
// Replaces R6's k_c3+k_c4: kills the z3+s3 HBM round-trip (~163MB) and c4's LN3
// recompute. LDS [28][17][64] h16 = 60928 B; phases: c3-big -> sync -> c4-big ->
// sync -> c3-small (reuses rows 0..3) -> sync -> c4-small.
__global__ __launch_bounds__(256, 2) void k_c34(const h16* __restrict__ z2,
                                                const float* __restrict__ w3,
                                                const float* __restrict__ w4,
                                                const float* __restrict__ f3,
                                                const float* __restrict__ f4,
                                                const float* __restrict__ l2g,
                                                const float* __restrict__ l2b,
                                                const float* __restrict__ l3g,
                                                const float* __restrict__ l3b,
                                                const float* __restrict__ l4g,
                                                const float* __restrict__ l4b,
                                                const float* __restrict__ s2,
                                                float* __restrict__ out) {
  __shared__ h16 nb[28][17][64];
  const int lane = threadIdx.x & 63;
  const int w = threadIdx.x >> 6;
  const int d = (int)blockIdx.x * 64 + lane;
  const int bi = d >> 4, u = d & 15;
  const int cobase = 7 * w;

  // ---- c3 big: conv3 + LN3 + ReLU -> nb[0..27] ----
  {
    float acc[7][17];
#pragma unroll
    for (int j = 0; j < 7; ++j)
#pragma unroll
      for (int p = 0; p < 17; ++p) acc[j][p] = 0.f;
#pragma unroll 1
    for (int ci = 0; ci < 28; ++ci) {
      float mu = s2[(size_t)ci * NS + d];
      float inv = s2[(size_t)(28 + ci) * NS + d];
      float n[35];
#pragma unroll
      for (int t = 0; t < 35; ++t) {
        float raw = (float)z2[(size_t)(ci * 35 + t) * NS + d];
        n[t] = fmaxf(fmaf((raw - mu) * inv, l2g[t], l2b[t]), 0.f);
      }
#pragma unroll
      for (int j = 0; j < 7; ++j) {
        const float* wp = w3 + (cobase + j) * 84 + ci * 3;
        float w0 = wp[0], w1v = wp[1], w2v = wp[2];
#pragma unroll
        for (int p = 0; p < 17; ++p)
          acc[j][p] = fmaf(n[2 * p], w0,
                      fmaf(n[2 * p + 1], w1v,
                      fmaf(n[2 * p + 2], w2v, acc[j][p])));
      }
    }
#pragma unroll
    for (int j = 0; j < 7; ++j) {
      float sum = 0.f, sq = 0.f;
#pragma unroll
      for (int p = 0; p < 17; ++p) { sum += acc[j][p]; sq = fmaf(acc[j][p], acc[j][p], sq); }
      float mu = sum * (1.0f / 17.0f);
      float var = sq * (1.0f / 17.0f) - mu * mu;
      float inv = rsqrtf(var + 1e-5f);
#pragma unroll
      for (int p = 0; p < 17; ++p)
        nb[cobase + j][p][lane] =
            (h16)fmaxf(fmaf((acc[j][p] - mu) * inv, l3g[p], l3b[p]), 0.f);
    }
  }
  __syncthreads();

  // ---- c4 big: conv4 + LN4 + ReLU -> out ----
  {
    float a4[7][8];
#pragma unroll
    for (int j = 0; j < 7; ++j)
#pragma unroll
      for (int p = 0; p < 8; ++p) a4[j][p] = 0.f;
#pragma unroll 1
    for (int ci = 0; ci < 28; ++ci) {
      float n[17];
#pragma unroll
      for (int t = 0; t < 17; ++t) n[t] = (float)nb[ci][t][lane];
#pragma unroll
      for (int j = 0; j < 7; ++j) {
        const float* wp = w4 + (cobase + j) * 84 + ci * 3;
        float w0 = wp[0], w1v = wp[1], w2v = wp[2];
#pragma unroll
        for (int p = 0; p < 8; ++p)
          a4[j][p] = fmaf(n[2 * p], w0,
                     fmaf(n[2 * p + 1], w1v,
                     fmaf(n[2 * p + 2], w2v, a4[j][p])));
      }
    }
#pragma unroll
    for (int j = 0; j < 7; ++j) {
      const int co = cobase + j;
      float sum = 0.f, sq = 0.f;
#pragma unroll
      for (int p = 0; p < 8; ++p) { sum += a4[j][p]; sq = fmaf(a4[j][p], a4[j][p], sq); }
      float mu = sum * 0.125f;
      float var = sq * 0.125f - mu * mu;
      float inv = rsqrtf(var + 1e-5f);
      const int ch = (u < 8) ? co : (28 + co);
      float* op = out + (size_t)bi * 4096 + (size_t)ch * 64 + (size_t)(u & 7) * 8;
      float o[8];
#pragma unroll
      for (int p = 0; p < 8; ++p)
        o[p] = fmaxf(fmaf((a4[j][p] - mu) * inv, l4g[p], l4b[p]), 0.f);
      *(float4*)(op) = make_float4(o[0], o[1], o[2], o[3]);
      *(float4*)(op + 4) = make_float4(o[4], o[5], o[6], o[7]);
    }
  }
  __syncthreads();   // all c4-big LDS reads done before small overwrites rows 0..3

  // ---- c3 small: conv3 + LN3 + ReLU -> nb[0..3] ----
  {
    float acc[17];
#pragma unroll
    for (int p = 0; p < 17; ++p) acc[p] = 0.f;
    const int co = w;
#pragma unroll 1
    for (int ci = 0; ci < 4; ++ci) {
      float mu = s2[(size_t)(56 + ci) * NS + d];
      float inv = s2[(size_t)(60 + ci) * NS + d];
      float n[35];
#pragma unroll
      for (int t = 0; t < 35; ++t) {
        float raw = (float)z2[(size_t)(980 + ci * 35 + t) * NS + d];
        n[t] = fmaxf(fmaf((raw - mu) * inv, l2g[t], l2b[t]), 0.f);
      }
      const float* wp = f3 + co * 12 + ci * 3;
      float w0 = wp[0], w1v = wp[1], w2v = wp[2];
#pragma unroll
      for (int p = 0; p < 17; ++p)
        acc[p] = fmaf(n[2 * p], w0,
                 fmaf(n[2 * p + 1], w1v,
                 fmaf(n[2 * p + 2], w2v, acc[p])));
    }
    float sum = 0.f, sq = 0.f;
#pragma unroll
    for (int p = 0; p < 17; ++p) { sum += acc[p]; sq = fmaf(acc[p], acc[p], sq); }
    float mu = sum * (1.0f / 17.0f);
    float var = sq * (1.0f / 17.0f) - mu * mu;
    float inv = rsqrtf(var + 1e-5f);
#pragma unroll
    for (int p = 0; p < 17; ++p)
      nb[w][p][lane] =
          (h16)fmaxf(fmaf((acc[p] - mu) * inv, l3g[p], l3b[p]), 0.f);
  }
  __syncthreads();

  // ---- c4 small: conv4 + LN4 + ReLU -> out ----
  {
    float a4[8];
#pragma unroll
    for (int p = 0; p < 8; ++p) a4[p] = 0.f;
    const int co = w;
#pragma unroll 1
    for (int ci = 0; ci < 4; ++ci) {
      float n[17];
#pragma unroll
      for (int t = 0; t < 17; ++t) n[t] = (float)nb[ci][t][lane];
      const float* wp = f4 + co * 12 + ci * 3;
      float w0 = wp[0], w1v = wp[1], w2v = wp[2];
#pragma unroll
      for (int p = 0; p < 8; ++p)
        a4[p] = fmaf(n[2 * p], w0,
                fmaf(n[2 * p + 1], w1v,
                fmaf(n[2 * p + 2], w2v, a4[p])));
    }
    float sum = 0.f, sq = 0.f;
#pragma unroll
    for (int p = 0; p < 8; ++p) { sum += a4[p]; sq = fmaf(a4[p], a4[p], sq); }
    float mu = sum * 0.125f;
    float var = sq * 0.125f - mu * mu;
    float inv = rsqrtf(var + 1e-5f);
    const int ch = (u < 8) ? (56 + co) : (60 + co);
    float* op = out + (size_t)bi * 4096 + (size_t)ch * 64 + (size_t)(u & 7) * 8;
    float o[8];
#pragma unroll
    for (int p = 0; p < 8; ++p)
      o[p] = fmaxf(fmaf((a4[p] - mu) * inv, l4g[p], l4b[p]), 0.f);
    *(float4*)(op) = make_float4(o[0], o[1], o[2], o[3]);
    *(float4*)(op + 4) = make_float4(o[4], o[5], o[6], o[7]);
  }
}

extern "C" void kernel_launch(void* const* d_in, const int* in_sizes, int n_in,
                              void* d_out, int out_size, void* d_ws, size_t ws_size,
                              hipStream_t stream) {
  const float* x   = (const float*)d_in[0];
  const float* w1  = (const float*)d_in[1];
  const float* w2  = (const float*)d_in[2];
  const float* w3  = (const float*)d_in[3];
  const float* w4  = (const float*)d_in[4];
  const float* f1  = (const float*)d_in[5];
  const float* f2  = (const float*)d_in[6];
  const float* f3  = (const float*)d_in[7];
  const float* f4  = (const float*)d_in[8];
  const float* l1g = (const float*)d_in[9];
  const float* l1b = (const float*)d_in[10];
  const float* l2g = (const float*)d_in[11];
  const float* l2b = (const float*)d_in[12];
  const float* l3g = (const float*)d_in[13];
  const float* l3b = (const float*)d_in[14];
  const float* l4g = (const float*)d_in[15];
  const float* l4b = (const float*)d_in[16];
  float* out = (float*)d_out;
  char* wsb = (char*)d_ws;

  // workspace carve (bytes); z3/s3 slots unused after c34 fusion
  float* xv = (float*)(wsb + 0);                      // [143][VSTR] f32
  h16*   fm = (h16*)(wsb + 74973184ull);              // [143][VSTR] f16
  h16*   z2 = (h16*)(wsb + 112459776ull);             // big [980][NS] + small [140][NS]
  float* s1 = (float*)(wsb + 330563584ull);           // 40 rows [NS] f32
  float* s2 = (float*)(wsb + 341049344ull);           // 64 rows
  float* tw = (float*)(wsb + 374603776ull);           // [72][286] f32

  k_gather<<<4097, 256, 0, stream>>>(x, xv, tw);
  k_dft<<<512, 256, 0, stream>>>(xv, tw, fm);
  k_c1<<<1024, 256, 0, stream>>>(xv, fm, w1, f1, s1);
  k_c2<<<1024, 256, 0, stream>>>(xv, fm, w1, w2, f1, f2, l1g, l1b, s1, z2, s2);
  k_c34<<<1024, 256, 0, stream>>>(z2, w3, w4, f3, f4, l2g, l2b, l3g, l3b, l4g, l4b,
                                  s2, out);
}

// Round 10
// 1146.748 us; speedup vs baseline: 1.6324x; 1.6324x over previous
//
#include <hip/hip_runtime.h>
#include <math.h>

typedef _Float16 h16;
typedef _Float16 h16x2 __attribute__((ext_vector_type(2)));

#define NS 65536      // samples per class (big / small)
#define VSTR 131072   // xvec/fmag column count (4096 batches * 32 vectors)

// ---------------- k_gather: x -> xvec columns (fp32); block 4096 builds twiddles ----
__global__ __launch_bounds__(256) void k_gather(const float* __restrict__ x,
                                                float* __restrict__ xv,
                                                float* __restrict__ tw) {
  const int b = blockIdx.x;
  if (b < 4096) {
    const float* xb = x + (size_t)b * 9152;
    const int base = b * 32;
    for (int i = threadIdx.x; i < 9152; i += 256) {
      float v = xb[i];
      int c = i >> 6, pos = i & 63;
      if (pos >= 24 && pos < 40)
        xv[(size_t)c * VSTR + base + (pos - 24)] = v;
      int wc = pos & 7;
      if (wc == 3 || wc == 4)
        xv[(size_t)c * VSTR + base + 16 + ((pos >> 3) << 1) + (wc - 3)] = v;
    }
  } else {
    for (int i = threadIdx.x; i < 10296; i += 256) {
      int k = i / 143, n = i - k * 143;
      int e = (k * n) % 143;
      float ang = 6.2831853071795864769f * (float)e / 143.0f;
      float s, c;
      sincosf(ang, &s, &c);
      tw[2 * i] = c;
      tw[2 * i + 1] = s;
    }
  }
}

// ---------------- k_dft: lane = vector, column in VGPRs, uniform twiddles ----
__global__ __launch_bounds__(256, 2) void k_dft(const float* __restrict__ xv,
                                                const float* __restrict__ tw,
                                                h16* __restrict__ fm) {
  const int v = blockIdx.x * 256 + threadIdx.x;
  float xr[143];
#pragma unroll
  for (int n = 0; n < 143; ++n) xr[n] = xv[(size_t)n * VSTR + v];

  for (int k = 0; k < 72; ++k) {
    const float* __restrict__ twk = tw + k * 286;
    float re = 0.f, im = 0.f;
#pragma unroll
    for (int n = 0; n < 143; ++n) {
      re = fmaf(xr[n], twk[2 * n], re);
      im = fmaf(xr[n], twk[2 * n + 1], im);
    }
    float m = sqrtf(re * re + im * im);
    fm[(size_t)k * VSTR + v] = (h16)m;
    if (k) fm[(size_t)(143 - k) * VSTR + v] = (h16)m;
  }
}

// R10 notes:
// - c34 fusion REFUTED by R9 (949us vs 238us for separate c3+c4; VALUBusy 16.5%,
//   128 arch-VGPR + acc juggling, LDS-capped occupancy). z3/s3 round-trip costs
//   only ~50us of HBM BW -- fusions must be register/occupancy-neutral to win.
//   k_c3/k_c4 reverted to R6 verbatim.
// - c12 fusion applied (deletes k_c1's full 112MB re-read pass): pass-1 computes
//   wave-chunked conv1 LN1 stats (tiny state: ps[20]/pq[20]), LDS-reduced into
//   mu/inv rows; pass-2 is the R6-verified c2 body reading stats from LDS.
//   Pass-2 xv/fm re-reads hit L2/L3 (total 112MB < 256MB L3).
// All blocks UNIFORM (R6 invariant).
__device__ __forceinline__ void smap(int& d, int& w, int& va, int& vb,
                                     int& bi, int& u) {
  int lane = threadIdx.x & 63;
  w = __builtin_amdgcn_readfirstlane(threadIdx.x >> 6);
  d = (int)blockIdx.x * 64 + lane;
  bi = d >> 4;
  u = d & 15;
  va = (u < 8) ? bi * 32 + ((u >> 2) << 3) + ((u & 3) << 1)
               : bi * 32 + 16 + ((u & 7) << 1);
  vb = va + 1;
}

// -------- k_c12: conv1 stats (pass 1) + conv1/LN1/conv2/LN2 -> z2 (pass 2) -----
__global__ __launch_bounds__(256, 2) void k_c12(const float* __restrict__ xv,
                                                const h16* __restrict__ fm,
                                                const float* __restrict__ w1,
                                                const float* __restrict__ w2,
                                                const float* __restrict__ f1,
                                                const float* __restrict__ f2,
                                                const float* __restrict__ l1g,
                                                const float* __restrict__ l1b,
                                                h16* __restrict__ z2,
                                                float* __restrict__ s2) {
  __shared__ float red[4][32][64];
  const int lane = threadIdx.x & 63;
  const int w = threadIdx.x >> 6;           // wave id
  const int d = (int)blockIdx.x * 64 + lane;
  const int bi = d >> 4, u = d & 15;
  const int va = (u < 8) ? bi * 32 + ((u >> 2) << 3) + ((u & 3) << 1)
                         : bi * 32 + 16 + ((u & 7) << 1);

  // ================= pass 1: conv1 -> LN1 stats (chunked, LDS-reduced) ========
  {
    float ps[20], pq[20];
#pragma unroll
    for (int j = 0; j < 20; ++j) { ps[j] = 0.f; pq[j] = 0.f; }
    const int ips = 18 * w;
    const int ipe = (ips + 18 < 71) ? (ips + 18) : 71;   // chunks 18,18,18,17
    float2 r0 = *(const float2*)(xv + (size_t)(2 * ips) * VSTR + va);
    float A0 = r0.x, B0 = r0.y;
    h16x2 g0 = *(const h16x2*)(fm + (size_t)(2 * ips) * VSTR + va);
    float FA0 = (float)g0.x, FB0 = (float)g0.y;
#pragma unroll 1
    for (int ip = ips; ip < ipe; ++ip) {
      float2 r1 = *(const float2*)(xv + (size_t)(2 * ip + 1) * VSTR + va);
      float2 r2 = *(const float2*)(xv + (size_t)(2 * ip + 2) * VSTR + va);
      h16x2 g1 = *(const h16x2*)(fm + (size_t)(2 * ip + 1) * VSTR + va);
      h16x2 g2 = *(const h16x2*)(fm + (size_t)(2 * ip + 2) * VSTR + va);
#pragma unroll
      for (int c = 0; c < 16; ++c) {
        const float* wp = w1 + c * 6;
        float v = A0 * wp[0];
        v = fmaf(r1.x, wp[1], v); v = fmaf(r2.x, wp[2], v);
        v = fmaf(B0, wp[3], v); v = fmaf(r1.y, wp[4], v); v = fmaf(r2.y, wp[5], v);
        ps[c] += v; pq[c] = fmaf(v, v, pq[c]);
      }
      float FA1 = (float)g1.x, FB1 = (float)g1.y;
      float FA2 = (float)g2.x, FB2 = (float)g2.y;
#pragma unroll
      for (int c = 0; c < 4; ++c) {
        const float* wp = f1 + c * 6;
        float v = FA0 * wp[0];
        v = fmaf(FA1, wp[1], v); v = fmaf(FA2, wp[2], v);
        v = fmaf(FB0, wp[3], v); v = fmaf(FB1, wp[4], v); v = fmaf(FB2, wp[5], v);
        ps[16 + c] += v; pq[16 + c] = fmaf(v, v, pq[16 + c]);
      }
      A0 = r2.x; B0 = r2.y; FA0 = FA2; FB0 = FB2;
    }
    // two-phase reduce; wave w owns channels 5w..5w+4 of the 20
#pragma unroll
    for (int j = 0; j < 20; ++j) red[w][j][lane] = ps[j];
    __syncthreads();
    float ts[5];
#pragma unroll
    for (int t = 0; t < 5; ++t) {
      int c = 5 * w + t;
      ts[t] = red[0][c][lane] + red[1][c][lane] + red[2][c][lane] + red[3][c][lane];
    }
    __syncthreads();
#pragma unroll
    for (int j = 0; j < 20; ++j) red[w][j][lane] = pq[j];
    __syncthreads();
    float tmu[5], tiv[5];
#pragma unroll
    for (int t = 0; t < 5; ++t) {
      int c = 5 * w + t;
      float tq = red[0][c][lane] + red[1][c][lane] + red[2][c][lane] + red[3][c][lane];
      float mu = ts[t] * (1.0f / 71.0f);
      float var = tq * (1.0f / 71.0f) - mu * mu;
      tmu[t] = mu; tiv[t] = rsqrtf(var + 1e-5f);
    }
    __syncthreads();
#pragma unroll
    for (int t = 0; t < 5; ++t) {
      int c = 5 * w + t;
      red[0][c][lane] = tmu[t];     // mu rows: red[0][0..19]
      red[1][c][lane] = tiv[t];     // inv rows: red[1][0..19]
    }
    __syncthreads();
  }

  // ================= pass 2: conv1(once)/LN1/conv2 + LN2 partials =============
  const int ps2 = w * 9;
  const int pe2 = (ps2 + 9 < 35) ? (ps2 + 9) : 35;

  float sum[28], sq[28];     // big LN2 partials
  float sums[4], sqs[4];     // small LN2 partials

  // ---- big phase ----
  {
    float mu1[16], inv1[16];
#pragma unroll
    for (int c = 0; c < 16; ++c) {
      mu1[c] = red[0][c][lane];
      inv1[c] = red[1][c][lane];
    }
#pragma unroll
    for (int j = 0; j < 28; ++j) { sum[j] = 0.f; sq[j] = 0.f; }

    float n0[16], n1[16], n2[16];
    float a2, b2, a3, b3, a4, b4, a5, b5, a6, b6;

    {
      float2 r0 = *(const float2*)(xv + (size_t)(4 * ps2) * VSTR + va);
      float2 r1 = *(const float2*)(xv + (size_t)(4 * ps2 + 1) * VSTR + va);
      float2 r2 = *(const float2*)(xv + (size_t)(4 * ps2 + 2) * VSTR + va);
      a2 = r2.x; b2 = r2.y;
      const float gg = l1g[2 * ps2], bb = l1b[2 * ps2];
#pragma unroll
      for (int c = 0; c < 16; ++c) {
        const float* wp = w1 + c * 6;
        float v = r0.x * wp[0];
        v = fmaf(r1.x, wp[1], v); v = fmaf(a2, wp[2], v);
        v = fmaf(r0.y, wp[3], v); v = fmaf(r1.y, wp[4], v); v = fmaf(b2, wp[5], v);
        n0[c] = fmaxf(fmaf((v - mu1[c]) * inv1[c], gg, bb), 0.f);
      }
      float2 r3 = *(const float2*)(xv + (size_t)(4 * ps2 + 3) * VSTR + va);
      float2 r4 = *(const float2*)(xv + (size_t)(4 * ps2 + 4) * VSTR + va);
      float2 r5 = *(const float2*)(xv + (size_t)(4 * ps2 + 5) * VSTR + va);
      float2 r6 = *(const float2*)(xv + (size_t)(4 * ps2 + 6) * VSTR + va);
      a3 = r3.x; b3 = r3.y; a4 = r4.x; b4 = r4.y;
      a5 = r5.x; b5 = r5.y; a6 = r6.x; b6 = r6.y;
    }

#pragma unroll 1
    for (int p = ps2; p < pe2; ++p) {
      {
        const float gg = l1g[2 * p + 1], bb = l1b[2 * p + 1];
#pragma unroll
        for (int c = 0; c < 16; ++c) {
          const float* wp = w1 + c * 6;
          float v = a2 * wp[0];
          v = fmaf(a3, wp[1], v); v = fmaf(a4, wp[2], v);
          v = fmaf(b2, wp[3], v); v = fmaf(b3, wp[4], v); v = fmaf(b4, wp[5], v);
          n1[c] = fmaxf(fmaf((v - mu1[c]) * inv1[c], gg, bb), 0.f);
        }
      }
      {
        const float gg = l1g[2 * p + 2], bb = l1b[2 * p + 2];
#pragma unroll
        for (int c = 0; c < 16; ++c) {
          const float* wp = w1 + c * 6;
          float v = a4 * wp[0];
          v = fmaf(a5, wp[1], v); v = fmaf(a6, wp[2], v);
          v = fmaf(b4, wp[3], v); v = fmaf(b5, wp[4], v); v = fmaf(b6, wp[5], v);
          n2[c] = fmaxf(fmaf((v - mu1[c]) * inv1[c], gg, bb), 0.f);
        }
      }
      a2 = a6; b2 = b6;
      {
        const int rbase = (p < 34) ? (4 * p + 7) : 139;
        const float* rp = xv + (size_t)rbase * VSTR + va;
        float2 r3 = *(const float2*)(rp);
        float2 r4 = *(const float2*)(rp + (size_t)VSTR);
        float2 r5 = *(const float2*)(rp + (size_t)2 * VSTR);
        float2 r6 = *(const float2*)(rp + (size_t)3 * VSTR);
        a3 = r3.x; b3 = r3.y; a4 = r4.x; b4 = r4.y;
        a5 = r5.x; b5 = r5.y; a6 = r6.x; b6 = r6.y;
      }
#pragma unroll
      for (int j = 0; j < 28; ++j) {
        const float* wp = w2 + j * 48;
        float acc = 0.f;
#pragma unroll
        for (int ci = 0; ci < 16; ++ci) {
          acc = fmaf(n0[ci], wp[ci * 3 + 0], acc);
          acc = fmaf(n1[ci], wp[ci * 3 + 1], acc);
          acc = fmaf(n2[ci], wp[ci * 3 + 2], acc);
        }
        z2[(size_t)(j * 35 + p) * NS + d] = (h16)acc;
        sum[j] += acc; sq[j] = fmaf(acc, acc, sq[j]);
      }
#pragma unroll
      for (int c = 0; c < 16; ++c) n0[c] = n2[c];
    }
  }

  // ---- small phase ----
  {
    float mu1[4], inv1[4];
#pragma unroll
    for (int c = 0; c < 4; ++c) {
      mu1[c] = red[0][16 + c][lane];
      inv1[c] = red[1][16 + c][lane];
    }
#pragma unroll
    for (int c = 0; c < 4; ++c) { sums[c] = 0.f; sqs[c] = 0.f; }
    float n0[4], n1[4], n2[4];
    float a2, b2, a3, b3, a4, b4, a5, b5, a6, b6;

    {
      h16x2 r0 = *(const h16x2*)(fm + (size_t)(4 * ps2) * VSTR + va);
      h16x2 r1 = *(const h16x2*)(fm + (size_t)(4 * ps2 + 1) * VSTR + va);
      h16x2 r2 = *(const h16x2*)(fm + (size_t)(4 * ps2 + 2) * VSTR + va);
      float a0 = (float)r0.x, b0 = (float)r0.y;
      float a1 = (float)r1.x, b1 = (float)r1.y;
      a2 = (float)r2.x; b2 = (float)r2.y;
      const float gg = l1g[2 * ps2], bb = l1b[2 * ps2];
#pragma unroll
      for (int c = 0; c < 4; ++c) {
        const float* wp = f1 + c * 6;
        float v = a0 * wp[0];
        v = fmaf(a1, wp[1], v); v = fmaf(a2, wp[2], v);
        v = fmaf(b0, wp[3], v); v = fmaf(b1, wp[4], v); v = fmaf(b2, wp[5], v);
        n0[c] = fmaxf(fmaf((v - mu1[c]) * inv1[c], gg, bb), 0.f);
      }
      h16x2 r3 = *(const h16x2*)(fm + (size_t)(4 * ps2 + 3) * VSTR + va);
      h16x2 r4 = *(const h16x2*)(fm + (size_t)(4 * ps2 + 4) * VSTR + va);
      h16x2 r5 = *(const h16x2*)(fm + (size_t)(4 * ps2 + 5) * VSTR + va);
      h16x2 r6 = *(const h16x2*)(fm + (size_t)(4 * ps2 + 6) * VSTR + va);
      a3 = (float)r3.x; b3 = (float)r3.y; a4 = (float)r4.x; b4 = (float)r4.y;
      a5 = (float)r5.x; b5 = (float)r5.y; a6 = (float)r6.x; b6 = (float)r6.y;
    }

#pragma unroll 1
    for (int p = ps2; p < pe2; ++p) {
      {
        const float gg = l1g[2 * p + 1], bb = l1b[2 * p + 1];
#pragma unroll
        for (int c = 0; c < 4; ++c) {
          const float* wp = f1 + c * 6;
          float v = a2 * wp[0];
          v = fmaf(a3, wp[1], v); v = fmaf(a4, wp[2], v);
          v = fmaf(b2, wp[3], v); v = fmaf(b3, wp[4], v); v = fmaf(b4, wp[5], v);
          n1[c] = fmaxf(fmaf((v - mu1[c]) * inv1[c], gg, bb), 0.f);
        }
      }
      {
        const float gg = l1g[2 * p + 2], bb = l1b[2 * p + 2];
#pragma unroll
        for (int c = 0; c < 4; ++c) {
          const float* wp = f1 + c * 6;
          float v = a4 * wp[0];
          v = fmaf(a5, wp[1], v); v = fmaf(a6, wp[2], v);
          v = fmaf(b4, wp[3], v); v = fmaf(b5, wp[4], v); v = fmaf(b6, wp[5], v);
          n2[c] = fmaxf(fmaf((v - mu1[c]) * inv1[c], gg, bb), 0.f);
        }
      }
      a2 = a6; b2 = b6;
      {
        const int rbase = (p < 34) ? (4 * p + 7) : 139;
        const h16* rp = fm + (size_t)rbase * VSTR + va;
        h16x2 r3 = *(const h16x2*)(rp);
        h16x2 r4 = *(const h16x2*)(rp + (size_t)VSTR);
        h16x2 r5 = *(const h16x2*)(rp + (size_t)2 * VSTR);
        h16x2 r6 = *(const h16x2*)(rp + (size_t)3 * VSTR);
        a3 = (float)r3.x; b3 = (float)r3.y; a4 = (float)r4.x; b4 = (float)r4.y;
        a5 = (float)r5.x; b5 = (float)r5.y; a6 = (float)r6.x; b6 = (float)r6.y;
      }
#pragma unroll
      for (int co = 0; co < 4; ++co) {
        const float* wpo = f2 + co * 12;
        float acc = 0.f;
#pragma unroll
        for (int c = 0; c < 4; ++c) acc = fmaf(n0[c], wpo[c * 3 + 0], acc);
#pragma unroll
        for (int c = 0; c < 4; ++c) acc = fmaf(n1[c], wpo[c * 3 + 1], acc);
#pragma unroll
        for (int c = 0; c < 4; ++c) acc = fmaf(n2[c], wpo[c * 3 + 2], acc);
        z2[(size_t)(980 + co * 35 + p) * NS + d] = (h16)acc;
        sums[co] += acc; sqs[co] = fmaf(acc, acc, sqs[co]);
      }
#pragma unroll
      for (int c = 0; c < 4; ++c) n0[c] = n2[c];
    }
  }

  // ============ cross-wave LN2-stat reduction (red reused; sync first) ========
  __syncthreads();
#pragma unroll
  for (int j = 0; j < 28; ++j) red[w][j][lane] = sum[j];
#pragma unroll
  for (int c = 0; c < 4; ++c) red[w][28 + c][lane] = sums[c];
  __syncthreads();
  const int jb = 7 * w;
  float fs[7], fq[7];
#pragma unroll
  for (int t = 0; t < 7; ++t)
    fs[t] = red[0][jb + t][lane] + red[1][jb + t][lane] +
            red[2][jb + t][lane] + red[3][jb + t][lane];
  float fss = red[0][28 + w][lane] + red[1][28 + w][lane] +
              red[2][28 + w][lane] + red[3][28 + w][lane];
  __syncthreads();
#pragma unroll
  for (int j = 0; j < 28; ++j) red[w][j][lane] = sq[j];
#pragma unroll
  for (int c = 0; c < 4; ++c) red[w][28 + c][lane] = sqs[c];
  __syncthreads();
#pragma unroll
  for (int t = 0; t < 7; ++t)
    fq[t] = red[0][jb + t][lane] + red[1][jb + t][lane] +
            red[2][jb + t][lane] + red[3][jb + t][lane];
  float fqs = red[0][28 + w][lane] + red[1][28 + w][lane] +
              red[2][28 + w][lane] + red[3][28 + w][lane];
#pragma unroll
  for (int t = 0; t < 7; ++t) {
    float mu = fs[t] * (1.0f / 35.0f);
    float var = fq[t] * (1.0f / 35.0f) - mu * mu;
    s2[(size_t)(jb + t) * NS + d] = mu;
    s2[(size_t)(28 + jb + t) * NS + d] = rsqrtf(var + 1e-5f);
  }
  {
    float mu = fss * (1.0f / 35.0f);
    float var = fqs * (1.0f / 35.0f) - mu * mu;
    s2[(size_t)(56 + w) * NS + d] = mu;
    s2[(size_t)(60 + w) * NS + d] = rsqrtf(var + 1e-5f);
  }
}

// -------- k_c3: LN2 + conv3 + LN3 stats -> z3  (R6 verbatim; big then small) ---
__global__ __launch_bounds__(256, 1) void k_c3(const h16* __restrict__ z2,
                                               const float* __restrict__ w3,
                                               const float* __restrict__ f3,
                                               const float* __restrict__ l2g,
                                               const float* __restrict__ l2b,
                                               const float* __restrict__ s2,
                                               h16* __restrict__ z3,
                                               float* __restrict__ s3) {
  int d, w, va, vb, bi, u;
  smap(d, w, va, vb, bi, u);

  // ---- big ----
  {
    float acc[7][17];
#pragma unroll
    for (int j = 0; j < 7; ++j)
#pragma unroll
      for (int p = 0; p < 17; ++p) acc[j][p] = 0.f;
    const int cobase = 7 * w;
#pragma unroll 1
    for (int ci = 0; ci < 28; ++ci) {
      float mu = s2[(size_t)ci * NS + d];
      float inv = s2[(size_t)(28 + ci) * NS + d];
      float n[35];
#pragma unroll
      for (int t = 0; t < 35; ++t) {
        float raw = (float)z2[(size_t)(ci * 35 + t) * NS + d];
        n[t] = fmaxf(fmaf((raw - mu) * inv, l2g[t], l2b[t]), 0.f);
      }
#pragma unroll
      for (int j = 0; j < 7; ++j) {
        const float* wp = w3 + (cobase + j) * 84 + ci * 3;
        float w0 = wp[0], w1v = wp[1], w2v = wp[2];
#pragma unroll
        for (int p = 0; p < 17; ++p)
          acc[j][p] = fmaf(n[2 * p], w0,
                      fmaf(n[2 * p + 1], w1v,
                      fmaf(n[2 * p + 2], w2v, acc[j][p])));
      }
    }
#pragma unroll
    for (int j = 0; j < 7; ++j) {
      const int co = cobase + j;
      float sum = 0.f, sq = 0.f;
#pragma unroll
      for (int p = 0; p < 17; ++p) {
        sum += acc[j][p]; sq = fmaf(acc[j][p], acc[j][p], sq);
        z3[(size_t)(co * 17 + p) * NS + d] = (h16)acc[j][p];
      }
      float mu = sum * (1.0f / 17.0f);
      float var = sq * (1.0f / 17.0f) - mu * mu;
      s3[(size_t)co * NS + d] = mu;
      s3[(size_t)(28 + co) * NS + d] = rsqrtf(var + 1e-5f);
    }
  }
  // ---- small ----
  {
    float acc[17];
#pragma unroll
    for (int p = 0; p < 17; ++p) acc[p] = 0.f;
    const int co = w;
#pragma unroll 1
    for (int ci = 0; ci < 4; ++ci) {
      float mu = s2[(size_t)(56 + ci) * NS + d];
      float inv = s2[(size_t)(60 + ci) * NS + d];
      float n[35];
#pragma unroll
      for (int t = 0; t < 35; ++t) {
        float raw = (float)z2[(size_t)(980 + ci * 35 + t) * NS + d];
        n[t] = fmaxf(fmaf((raw - mu) * inv, l2g[t], l2b[t]), 0.f);
      }
      const float* wp = f3 + co * 12 + ci * 3;
      float w0 = wp[0], w1v = wp[1], w2v = wp[2];
#pragma unroll
      for (int p = 0; p < 17; ++p)
        acc[p] = fmaf(n[2 * p], w0,
                 fmaf(n[2 * p + 1], w1v,
                 fmaf(n[2 * p + 2], w2v, acc[p])));
    }
    float sum = 0.f, sq = 0.f;
#pragma unroll
    for (int p = 0; p < 17; ++p) {
      sum += acc[p]; sq = fmaf(acc[p], acc[p], sq);
      z3[(size_t)(476 + co * 17 + p) * NS + d] = (h16)acc[p];
    }
    float mu = sum * (1.0f / 17.0f);
    float var = sq * (1.0f / 17.0f) - mu * mu;
    s3[(size_t)(56 + co) * NS + d] = mu;
    s3[(size_t)(60 + co) * NS + d] = rsqrtf(var + 1e-5f);
  }
}

// -------- k_c4: LN3 + conv4 + LN4 + ReLU + store  (R6 verbatim; big then small) ----
__global__ __launch_bounds__(256, 1) void k_c4(const h16* __restrict__ z3,
                                               const float* __restrict__ w4,
                                               const float* __restrict__ f4,
                                               const float* __restrict__ l3g,
                                               const float* __restrict__ l3b,
                                               const float* __restrict__ l4g,
                                               const float* __restrict__ l4b,
                                               const float* __restrict__ s3,
                                               float* __restrict__ out) {
  int d, w, va, vb, bi, u;
  smap(d, w, va, vb, bi, u);

  // ---- big ----
  {
    float acc[7][8];
#pragma unroll
    for (int j = 0; j < 7; ++j)
#pragma unroll
      for (int p = 0; p < 8; ++p) acc[j][p] = 0.f;
    const int cobase = 7 * w;
#pragma unroll 1
    for (int ci = 0; ci < 28; ++ci) {
      float mu = s3[(size_t)ci * NS + d];
      float inv = s3[(size_t)(28 + ci) * NS + d];
      float n[17];
#pragma unroll
      for (int t = 0; t < 17; ++t) {
        float raw = (float)z3[(size_t)(ci * 17 + t) * NS + d];
        n[t] = fmaxf(fmaf((raw - mu) * inv, l3g[t], l3b[t]), 0.f);
      }
#pragma unroll
      for (int j = 0; j < 7; ++j) {
        const float* wp = w4 + (cobase + j) * 84 + ci * 3;
        float w0 = wp[0], w1v = wp[1], w2v = wp[2];
#pragma unroll
        for (int p = 0; p < 8; ++p)
          acc[j][p] = fmaf(n[2 * p], w0,
                      fmaf(n[2 * p + 1], w1v,
                      fmaf(n[2 * p + 2], w2v, acc[j][p])));
      }
    }
#pragma unroll
    for (int j = 0; j < 7; ++j) {
      const int co = cobase + j;
      float sum = 0.f, sq = 0.f;
#pragma unroll
      for (int p = 0; p < 8; ++p) { sum += acc[j][p]; sq = fmaf(acc[j][p], acc[j][p], sq); }
      float mu = sum * 0.125f;
      float var = sq * 0.125f - mu * mu;
      float inv = rsqrtf(var + 1e-5f);
      const int ch = (u < 8) ? co : (28 + co);
      float* op = out + (size_t)bi * 4096 + (size_t)ch * 64 + (size_t)(u & 7) * 8;
      float o[8];
#pragma unroll
      for (int p = 0; p < 8; ++p)
        o[p] = fmaxf(fmaf((acc[j][p] - mu) * inv, l4g[p], l4b[p]), 0.f);
      *(float4*)(op) = make_float4(o[0], o[1], o[2], o[3]);
      *(float4*)(op + 4) = make_float4(o[4], o[5], o[6], o[7]);
    }
  }
  // ---- small ----
  {
    float acc[8];
#pragma unroll
    for (int p = 0; p < 8; ++p) acc[p] = 0.f;
    const int co = w;
#pragma unroll 1
    for (int ci = 0; ci < 4; ++ci) {
      float mu = s3[(size_t)(56 + ci) * NS + d];
      float inv = s3[(size_t)(60 + ci) * NS + d];
      float n[17];
#pragma unroll
      for (int t = 0; t < 17; ++t) {
        float raw = (float)z3[(size_t)(476 + ci * 17 + t) * NS + d];
        n[t] = fmaxf(fmaf((raw - mu) * inv, l3g[t], l3b[t]), 0.f);
      }
      const float* wp = f4 + co * 12 + ci * 3;
      float w0 = wp[0], w1v = wp[1], w2v = wp[2];
#pragma unroll
      for (int p = 0; p < 8; ++p)
        acc[p] = fmaf(n[2 * p], w0,
                 fmaf(n[2 * p + 1], w1v,
                 fmaf(n[2 * p + 2], w2v, acc[p])));
    }
    float sum = 0.f, sq = 0.f;
#pragma unroll
    for (int p = 0; p < 8; ++p) { sum += acc[p]; sq = fmaf(acc[p], acc[p], sq); }
    float mu = sum * 0.125f;
    float var = sq * 0.125f - mu * mu;
    float inv = rsqrtf(var + 1e-5f);
    const int ch = (u < 8) ? (56 + co) : (60 + co);
    float* op = out + (size_t)bi * 4096 + (size_t)ch * 64 + (size_t)(u & 7) * 8;
    float o[8];
#pragma unroll
    for (int p = 0; p < 8; ++p)
      o[p] = fmaxf(fmaf((acc[p] - mu) * inv, l4g[p], l4b[p]), 0.f);
    *(float4*)(op) = make_float4(o[0], o[1], o[2], o[3]);
    *(float4*)(op + 4) = make_float4(o[4], o[5], o[6], o[7]);
  }
}

extern "C" void kernel_launch(void* const* d_in, const int* in_sizes, int n_in,
                              void* d_out, int out_size, void* d_ws, size_t ws_size,
                              hipStream_t stream) {
  const float* x   = (const float*)d_in[0];
  const float* w1  = (const float*)d_in[1];
  const float* w2  = (const float*)d_in[2];
  const float* w3  = (const float*)d_in[3];
  const float* w4  = (const float*)d_in[4];
  const float* f1  = (const float*)d_in[5];
  const float* f2  = (const float*)d_in[6];
  const float* f3  = (const float*)d_in[7];
  const float* f4  = (const float*)d_in[8];
  const float* l1g = (const float*)d_in[9];
  const float* l1b = (const float*)d_in[10];
  const float* l2g = (const float*)d_in[11];
  const float* l2b = (const float*)d_in[12];
  const float* l3g = (const float*)d_in[13];
  const float* l3b = (const float*)d_in[14];
  const float* l4g = (const float*)d_in[15];
  const float* l4b = (const float*)d_in[16];
  float* out = (float*)d_out;
  char* wsb = (char*)d_ws;

  // workspace carve (bytes); s1 slot unused (c12 fusion keeps stats in LDS)
  float* xv = (float*)(wsb + 0);                      // [143][VSTR] f32
  h16*   fm = (h16*)(wsb + 74973184ull);              // [143][VSTR] f16
  h16*   z2 = (h16*)(wsb + 112459776ull);             // big [980][NS] + small [140][NS]
  h16*   z3 = (h16*)(wsb + 259260416ull);             // big [476][NS] + small [68][NS]
  float* s2 = (float*)(wsb + 341049344ull);           // 64 rows [NS] f32
  float* s3 = (float*)(wsb + 357826560ull);           // 64 rows
  float* tw = (float*)(wsb + 374603776ull);           // [72][286] f32

  k_gather<<<4097, 256, 0, stream>>>(x, xv, tw);
  k_dft<<<512, 256, 0, stream>>>(xv, tw, fm);
  k_c12<<<1024, 256, 0, stream>>>(xv, fm, w1, w2, f1, f2, l1g, l1b, z2, s2);
  k_c3<<<1024, 256, 0, stream>>>(z2, w3, f3, l2g, l2b, s2, z3, s3);
  k_c4<<<1024, 256, 0, stream>>>(z3, w4, f4, l3g, l3b, l4g, l4b, s3, out);
}